// Round 9
// baseline (487.115 us; speedup 1.0000x reference)
//
#include <hip/hip_runtime.h>
#include <hip/hip_bf16.h>

// Problem constants
#define Tt   50
#define Dd   64
#define NOUT 100
#define G4   512   // 4*H
#define K0S  72    // a0 LDS stride (64 x-cols + 8 pad)
#define K1P  264   // a1 LDS stride (256 + 8 pad)
#define BM   16    // batch rows per workgroup (grid 256 = 4096/16)

typedef __attribute__((ext_vector_type(8))) short  short8;
typedef __attribute__((ext_vector_type(4))) float  floatx4;

#if __has_builtin(__builtin_amdgcn_exp2f)
#define EXP2(v) __builtin_amdgcn_exp2f(v)
#else
#define EXP2(v) exp2f(v)
#endif
__device__ __forceinline__ float rcp_(float v) { return __builtin_amdgcn_rcpf(v); }
#define KN2L2E (-2.8853900817779268f)   // -2*log2(e), for tanh(c) with natural-units c

// LDS-only barrier: publishes ds_writes without draining vmcnt (out-stores /
// prefetch loads stay in flight across the barrier). All barrier-protected
// data in this kernel lives in LDS. __syncthreads() would force vmcnt(0).
#define BARRIER() asm volatile("s_waitcnt lgkmcnt(0)\n\ts_barrier" ::: "memory")

__device__ __forceinline__ short f2bf(float f) {
    __hip_bfloat16 h = __float2bfloat16(f);
    return *reinterpret_cast<const short*>(&h);
}

// ws layout (bytes):
//  w0f bf16[ 98304] @ 0        (layer0 [Wk0;Wr0] 192x512, frag order f=nt*6+kt, nt=w+8g, PRESCALED)
//  w1f bf16[131072] @ 196608   (layer1 [Wk1;Wr1] 256x512, frag order f=nt*8+kt, PRESCALED)
//  wdf bf16[  8192] @ 458752   (Wd 128x64, frag order f=nt*4+kt, unscaled)
//  b0f f32[512]     @ 475136   (PRESCALED)
//  b1f f32[512]     @ 477184   (PRESCALED)
//  bdf f32[64]      @ 479232   (unscaled)
#define W1F_OFF 196608
#define WDF_OFF 458752
#define B0F_OFF 475136
#define B1F_OFF 477184
#define BDF_OFF 479232

__global__ __launch_bounds__(256) void prep_kernel(
    const float* __restrict__ Wk0, const float* __restrict__ Wr0, const float* __restrict__ b0,
    const float* __restrict__ Wk1, const float* __restrict__ Wr1, const float* __restrict__ b1,
    const float* __restrict__ Wd,  const float* __restrict__ bd,  char* __restrict__ ws)
{
    int idx = blockIdx.x * 256 + threadIdx.x;
    short* w0f = (short*)ws;
    short* w1f = (short*)(ws + W1F_OFF);
    short* wdf = (short*)(ws + WDF_OFF);
    float* b0f = (float*)(ws + B0F_OFF);
    float* b1f = (float*)(ws + B1F_OFF);
    float* bdf = (float*)(ws + BDF_OFF);
    const float NL2E = -1.4426950408889634f;   // -log2(e): i,f,o (sigmoid)
    const float N2L2E = -2.8853900817779268f;  // -2log2(e): g (tanh)

    if (idx < 98304) {
        int f = idx >> 9, r = idx & 511;
        int lane = r >> 3, j = r & 7;
        int nt = f / 6, kt = f - nt * 6;
        int k = kt * 32 + (lane >> 4) * 8 + j;
        int col = nt * 16 + (lane & 15);
        float sc = ((col >> 7) == 2) ? N2L2E : NL2E;
        w0f[idx] = f2bf(sc * ((k < Dd) ? Wk0[k * G4 + col] : Wr0[(k - Dd) * G4 + col]));
    } else if (idx < 229376) {
        int i2 = idx - 98304;
        int f = i2 >> 9, r = i2 & 511;
        int lane = r >> 3, j = r & 7;
        int nt = f >> 3, kt = f & 7;
        int k = kt * 32 + (lane >> 4) * 8 + j;
        int col = nt * 16 + (lane & 15);
        float sc = ((col >> 7) == 2) ? N2L2E : NL2E;
        w1f[i2] = f2bf(sc * ((k < 128) ? Wk1[k * G4 + col] : Wr1[(k - 128) * G4 + col]));
    } else if (idx < 237568) {
        int i2 = idx - 229376;
        int f = i2 >> 9, r = i2 & 511;
        int lane = r >> 3, j = r & 7;
        int nt = f >> 2, kt = f & 3;
        int k = kt * 32 + (lane >> 4) * 8 + j;
        int col = nt * 16 + (lane & 15);
        wdf[i2] = f2bf(Wd[k * Dd + col]);
    } else if (idx < 237568 + 1088) {
        int i2 = idx - 237568;
        if (i2 < 512) {
            float sc = ((i2 >> 7) == 2) ? N2L2E : NL2E;
            b0f[i2] = sc * b0[i2];
        } else if (i2 < 1024) {
            int c = i2 - 512;
            float sc = ((c >> 7) == 2) ? N2L2E : NL2E;
            b1f[c] = sc * b1[c];
        } else bdf[i2 - 1024] = bd[i2 - 1024];
    }
}

// Dynamic LDS layout (bytes):
//  a0[2] @ 0      : 2 × 16*72*2  = 4608   (x/pred tiles, ping-pong by step parity)
//  a1[2] @ 4608   : 2 × 16*264*2 = 16896  (h0 | h1 tiles, ping-pong)
//  w0l   @ 21504  : 131072                (W0 pairs p=0..15, [p][wave][512])
//  blf   @ 152576 : 4096                  (bias table: [hu]{i,f,g,o} f32x4, L0 then L1)
//  total 156672 (153 KiB)
#define SM_A1  4608
#define SM_W0  21504
#define SM_BL  152576
#define SM_TOT 156672
#define A0SZ   1152   // shorts per a0 buffer
#define A1SZ   4224   // shorts per a1 buffer

#define MFMA_B16(A, B, C) __builtin_amdgcn_mfma_f32_16x16x32_bf16((A), (B), (C), 0, 0, 0)

// gate block, fused-rcp form (3 rcp/row instead of 5; algebraically identical):
//   sig(i)*tanh(g) = (1-Eg) / ((1+Ei)(1+Eg)),  E* = 2^(prescaled pre-activation)
//   sig(o)*tanh(c) = (1-Ec) / ((1+Eo)(1+Ec)),  Ec = e^(-2c)
#define GATES(ACC, CS, BASE, COLOFF)                                                     \
    _Pragma("unroll")                                                                    \
    for (int rr = 0; rr < 4; ++rr) {                                                     \
        float Ei = EXP2(ACC[0][rr]);                                                     \
        float Ef = EXP2(ACC[1][rr]);                                                     \
        float Eg = EXP2(ACC[2][rr]);                                                     \
        float Eo = EXP2(ACC[3][rr]);                                                     \
        float ig = (1.0f - Eg) * rcp_((1.0f + Ei) * (1.0f + Eg));                        \
        float c_ = fmaf(rcp_(1.0f + Ef), CS[rr], ig);                                    \
        CS[rr] = c_;                                                                     \
        float Ec = EXP2(c_ * KN2L2E);                                                    \
        float h_ = (1.0f - Ec) * rcp_((1.0f + Eo) * (1.0f + Ec));                        \
        (BASE)[(quad * 4 + rr) * K1P + (COLOFF) + hu] = f2bf(h_);                        \
    }

// acc init from the LDS bias table. VOLATILE so the compiler cannot hoist the
// read out of the loop and reconstitute 8 persistent bias VGPRs (the register
// diet is the whole point: the budget is within ~4 regs of the 256 cap).
#define ACC_INIT_L(ACC, LOFF)                                        \
    {                                                                \
        floatx4 bv_ = *(const volatile floatx4*)&blf[(LOFF) + hu * 4]; \
        ACC[0] = (floatx4){bv_[0], bv_[0], bv_[0], bv_[0]};          \
        ACC[1] = (floatx4){bv_[1], bv_[1], bv_[1], bv_[1]};          \
        ACC[2] = (floatx4){bv_[2], bv_[2], bv_[2], bv_[2]};          \
        ACC[3] = (floatx4){bv_[3], bv_[3], bv_[3], bv_[3]};          \
    }

// one L0 k-tile: kt<2 = x-part (a0p), kt>=2 = h0-part (a1q)
#define L0KT(KT)                                                                          \
    {                                                                                     \
        short8 af = ((KT) < 2)                                                            \
            ? *(const short8*)&a0p[l15 * K0S + (KT) * 32 + quad * 8]                      \
            : *(const short8*)&a1q[l15 * K1P + ((KT) - 2) * 32 + quad * 8];               \
        _Pragma("unroll")                                                                 \
        for (int g = 0; g < 4; ++g) {                                                     \
            const int pp = g * 6 + (KT);                                                  \
            short8 bfr = (pp < 16) ? *(const short8*)&w0l[((pp * 8 + w) << 9) + lane * 8] \
                                   : W0R[pp - 16];                                        \
            acc[g] = MFMA_B16(af, bfr, acc[g]);                                           \
        }                                                                                 \
    }

// one L1 k-tile (A from a1p, B from W1R)
#define L1KT(KT)                                                                          \
    {                                                                                     \
        short8 af = *(const short8*)&a1p[l15 * K1P + (KT) * 32 + quad * 8];               \
        _Pragma("unroll")                                                                 \
        for (int g = 0; g < 4; ++g)                                                       \
            acc[g] = MFMA_B16(af, W1R[g][KT], acc[g]);                                    \
    }

// grid 256, block 512 (8 waves), 1 block/CU. Wave w owns hidden cols 16w..16w+15.
// All weights CU-resident. REGISTER DISCIPLINE (hard-won): the 256-reg/wave
// unified budget is EXACTLY full. R1 (co-live acc pair), R3 (acc across dense
// barriers + backedge), R4 (x2 unroll) spilled 10-38%; R6: residency must be
// wave-uniform; R8: acc across barrier C alone overflowed by ~4 regs (+4MB
// scratch writes). R7 falsified LDS-bandwidth as the bottleneck -> the step is
// latency-bound (MFMA idles during gate TRANS and the serial dense window).
// This round: (a) BIAS DIET — the 8 persistent bias VGPRs move to a 4KB LDS
// table, re-read per ACC_INIT via a volatile ds_read_b128 (volatile defeats
// LICM re-hoisting); all 4 quads read the same address -> LDS broadcast, ~5cyc
// off critical path. (b) retry R8's AR-only L1-h1 hoist with the freed regs:
// h1'(t-1) (a1p cols 128..255) is published at D(t-1), so L1 kt4..7 issue
// between gates0 and C, filling the MFMA-idle gates0 window and halving the
// post-C MFMA chain. acc crosses ONLY barrier C. Split warm/AR loops (single
// schedule each); inter-loop barrier publishes h1'(48). Keeps: setprio bursts,
// split dense ad-chains, LDS-feedback-before-stores, LDS-only barriers,
// fused-rcp gates, h-first-x-last L0 order.
__global__ __launch_bounds__(512, 2) void lstm_kernel(
    const float* __restrict__ x, const char* __restrict__ ws, float* __restrict__ out)
{
    extern __shared__ char smem[];
    short* a0b = (short*)smem;                 // 2 buffers of A0SZ
    short* a1b = (short*)(smem + SM_A1);       // 2 buffers of A1SZ
    short* w0l = (short*)(smem + SM_W0);
    float* blf = (float*)(smem + SM_BL);       // bias table

    const short* w0f = (const short*)ws;
    const short* w1f = (const short*)(ws + W1F_OFF);
    const short* wdf = (const short*)(ws + WDF_OFF);
    const float* b0f = (const float*)(ws + B0F_OFF);
    const float* b1f = (const float*)(ws + B1F_OFF);
    const float* bdf = (const float*)(ws + BDF_OFF);

    const int tid  = threadIdx.x;
    const int w    = tid >> 6;        // wave 0..7
    const int lane = tid & 63;
    const int l15  = lane & 15;
    const int quad = lane >> 4;
    const int row0 = blockIdx.x * BM;

    // ---- one-time staging ----
    for (int i = tid; i < 2 * A0SZ; i += 512) a0b[i] = 0;
    for (int i = tid; i < 2 * A1SZ; i += 512) a1b[i] = 0;
    // W0 pairs p<16 -> LDS
    for (int c = tid; c < 8192; c += 512) {       // short8 chunks
        int e8 = c & 63;
        int wv = (c >> 6) & 7;
        int p  = c >> 9;                           // 0..15
        int g = p / 6, kt = p - g * 6;
        const short* src = w0f + ((((g * 8 + wv) * 6) + kt) << 9) + e8 * 8;
        *(short8*)&w0l[((p * 8 + wv) << 9) + e8 * 8] = *(const short8*)src;
    }
    // bias table: [hu]{i,f,g,o} for L0 (floats 0..511) and L1 (512..1023)
    if (tid < 128) {
        *(floatx4*)&blf[tid * 4] =
            (floatx4){b0f[tid], b0f[128 + tid], b0f[256 + tid], b0f[384 + tid]};
        *(floatx4*)&blf[512 + tid * 4] =
            (floatx4){b1f[tid], b1f[128 + tid], b1f[256 + tid], b1f[384 + tid]};
    }
    {   // stage x_0 -> a0[0]
        int cx = tid & 63, rg2 = tid >> 6;
        a0b[rg2 * K0S + cx]       = f2bf(x[(size_t)(row0 + rg2) * (Tt * Dd) + cx]);
        a0b[(rg2 + 8) * K0S + cx] = f2bf(x[(size_t)(row0 + rg2 + 8) * (Tt * Dd) + cx]);
    }

    // register-resident weights
    const short* w0rb = w0f + w * 3072 + lane * 8;
    const short* w1rb = w1f + w * 4096 + lane * 8;
    short8 W1R[4][8];
    #pragma unroll
    for (int g = 0; g < 4; ++g)
        #pragma unroll
        for (int kt = 0; kt < 8; ++kt)
            W1R[g][kt] = *(const short8*)(w1rb + g * 32768 + kt * 512);
    short8 W0R[8];   // pairs p = 16..23
    #pragma unroll
    for (int p = 16; p < 24; ++p) {
        int g = p / 6, kt = p - g * 6;
        W0R[p - 16] = *(const short8*)(w0rb + g * 24576 + kt * 512);
    }
    short8 WdR[4];
    if (w < 4) {
        #pragma unroll
        for (int kt = 0; kt < 4; ++kt)
            WdR[kt] = *(const short8*)(wdf + ((w * 4 + kt) << 9) + lane * 8);
    }

    const int hu = w * 16 + l15;
    const float bdv = bdf[(w & 3) * 16 + l15];

    float c0s[4] = {0.f, 0.f, 0.f, 0.f};
    float c1s[4] = {0.f, 0.f, 0.f, 0.f};

    const int colx = tid & 63, rg = tid >> 6;

    __syncthreads();   // staging complete (one full sync is fine here)

    // ================= warm loop: steps 0..48 (x-driven, 1 barrier/step) ====
    for (int step = 0; step < 49; ++step) {
        const int p = step & 1, q = p ^ 1;
        short* a0p = a0b + p * A0SZ;  short* a0q = a0b + q * A0SZ;
        short* a1p = a1b + p * A1SZ;  short* a1q = a1b + q * A1SZ;

        // issue next-x global loads early (consumed at step bottom); step 48
        // stages x(49), consumed by the first AR step.
        float xv0 = x[(size_t)(row0 + rg)     * (Tt * Dd) + (step + 1) * Dd + colx];
        float xv1 = x[(size_t)(row0 + rg + 8) * (Tt * Dd) + (step + 1) * Dd + colx];

        // ---------- layer 0: A = [x|h0], h-part first, x-part last ----------
        floatx4 acc[4];
        ACC_INIT_L(acc, 0);
        __builtin_amdgcn_s_setprio(1);
        L0KT(2) L0KT(3) L0KT(4) L0KT(5) L0KT(0) L0KT(1)
        __builtin_amdgcn_s_setprio(0);

        // ---------- gates layer 0 -> h0' into a1[p] cols 0..127 ----------
        GATES(acc, c0s, a1p, 0);

        // stage next x into a0[q] (before the barrier that publishes it)
        a0q[rg * K0S + colx]       = f2bf(xv0);
        a0q[(rg + 8) * K0S + colx] = f2bf(xv1);
        BARRIER();   // C: h0' (and next-x) visible

        // ---------- layer 1: A = a1[p] (h0' | h1) ----------
        ACC_INIT_L(acc, 512);
        __builtin_amdgcn_s_setprio(1);
        L1KT(0) L1KT(1) L1KT(2) L1KT(3) L1KT(4) L1KT(5) L1KT(6) L1KT(7)
        __builtin_amdgcn_s_setprio(0);

        // ---------- gates layer 1 -> h1' into a1[q] cols 128..255 ----------
        GATES(acc, c1s, a1q, 128);
    }

    BARRIER();   // publish h1'(48) so step 49 can hoist its L1 h1-half

    // ================= AR loop: steps 49..148 (dense head every step) =======
    for (int step = 49; step < 149; ++step) {
        const int p = step & 1, q = p ^ 1;
        short* a0p = a0b + p * A0SZ;  short* a0q = a0b + q * A0SZ;
        short* a1p = a1b + p * A1SZ;  short* a1q = a1b + q * A1SZ;

        // ---------- layer 0: A = [x|h0] (x = pred for step>49) ----------
        floatx4 acc[4];
        ACC_INIT_L(acc, 0);
        __builtin_amdgcn_s_setprio(1);
        L0KT(2) L0KT(3) L0KT(4) L0KT(5) L0KT(0) L0KT(1)
        __builtin_amdgcn_s_setprio(0);

        // ---------- gates layer 0 -> h0' into a1[p] cols 0..127 ----------
        GATES(acc, c0s, a1p, 0);

        // ---------- HOIST: L1 h1-half (kt4..7). a1p[128:256] = h1'(t-1),
        // published at D(t-1) (or the inter-loop barrier) -> no C needed.
        // Fills the MFMA-idle gates0 window; acc crosses only barrier C. ----
        ACC_INIT_L(acc, 512);
        __builtin_amdgcn_s_setprio(1);
        L1KT(4) L1KT(5) L1KT(6) L1KT(7)
        __builtin_amdgcn_s_setprio(0);

        BARRIER();   // C: h0' visible

        // ---------- layer 1 remainder: h0-half (kt0..3) ----------
        __builtin_amdgcn_s_setprio(1);
        L1KT(0) L1KT(1) L1KT(2) L1KT(3)
        __builtin_amdgcn_s_setprio(0);

        // ---------- gates layer 1 -> h1' into a1[q] cols 128..255 ----------
        GATES(acc, c1s, a1q, 128);

        // ---------- dense head: pred = h1' @ Wd + bd ----------
        BARRIER();   // D: h1' visible
        if (w < 4) {
            // two independent 2-deep MFMA chains (halves serial latency
            // in the D->E window), summed at the end
            floatx4 ad0 = (floatx4){bdv, bdv, bdv, bdv};
            floatx4 ad1 = (floatx4){0.f, 0.f, 0.f, 0.f};
            __builtin_amdgcn_s_setprio(1);
            {
                short8 a0_ = *(const short8*)&a1q[l15 * K1P + 128 +  0 + quad * 8];
                short8 a1_ = *(const short8*)&a1q[l15 * K1P + 128 + 32 + quad * 8];
                short8 a2_ = *(const short8*)&a1q[l15 * K1P + 128 + 64 + quad * 8];
                short8 a3_ = *(const short8*)&a1q[l15 * K1P + 128 + 96 + quad * 8];
                ad0 = MFMA_B16(a0_, WdR[0], ad0);
                ad1 = MFMA_B16(a1_, WdR[1], ad1);
                ad0 = MFMA_B16(a2_, WdR[2], ad0);
                ad1 = MFMA_B16(a3_, WdR[3], ad1);
            }
            __builtin_amdgcn_s_setprio(0);
            float pv0 = ad0[0] + ad1[0], pv1 = ad0[1] + ad1[1];
            float pv2 = ad0[2] + ad1[2], pv3 = ad0[3] + ad1[3];
            int col = w * 16 + l15;
            // LDS feedback first (barrier E waits only on these) ...
            a0q[(quad * 4 + 0) * K0S + col] = f2bf(pv0);
            a0q[(quad * 4 + 1) * K0S + col] = f2bf(pv1);
            a0q[(quad * 4 + 2) * K0S + col] = f2bf(pv2);
            a0q[(quad * 4 + 3) * K0S + col] = f2bf(pv3);
            // ... then fire-and-forget global stores (not tracked by lgkmcnt)
            int s = step - (Tt - 1);
            size_t ob = (size_t)(row0 + quad * 4) * (NOUT * Dd) + s * Dd + col;
            out[ob]                 = pv0;
            out[ob + 1 * NOUT * Dd] = pv1;
            out[ob + 2 * NOUT * Dd] = pv2;
            out[ob + 3 * NOUT * Dd] = pv3;
        }
        BARRIER();   // E: publish pred before next step's L0 reads a0[q]
    }
}

extern "C" void kernel_launch(void* const* d_in, const int* in_sizes, int n_in,
                              void* d_out, int out_size, void* d_ws, size_t ws_size,
                              hipStream_t stream)
{
    (void)in_sizes; (void)n_in; (void)out_size; (void)ws_size;
    static_assert(SM_TOT <= 160 * 1024, "LDS budget");
    hipFuncSetAttribute(reinterpret_cast<const void*>(lstm_kernel),
                        hipFuncAttributeMaxDynamicSharedMemorySize, SM_TOT);
    prep_kernel<<<933, 256, 0, stream>>>(
        (const float*)d_in[1], (const float*)d_in[2], (const float*)d_in[3],
        (const float*)d_in[4], (const float*)d_in[5], (const float*)d_in[6],
        (const float*)d_in[7], (const float*)d_in[8], (char*)d_ws);
    lstm_kernel<<<256, 512, SM_TOT, stream>>>(
        (const float*)d_in[0], (const char*)d_ws, (float*)d_out);
}